// Round 6
// baseline (338.820 us; speedup 1.0000x reference)
//
#include <hip/hip_runtime.h>

typedef _Float16 f16;
typedef _Float16 f16x8 __attribute__((ext_vector_type(8)));
typedef float f32x4 __attribute__((ext_vector_type(4)));

#define NB 5
#define H 64
#define DIN 100
#define NT 256
#define MAIN_BLOCKS 768
#define SEG 4096

// packed weight-fragment regions in d_ws, units of 16B frags
#define FR_W1   0      // 4 ksteps * 4 mtiles * 64 lanes = 1024 frags
#define FR_W2   1024   // 2 * 4 * 64 = 512
#define FR_HD   1536   // q*1024 + layer*512 + (s*4+mt)*64 + lane ; 5*2*512 = 5120
#define FR_TOT  6656
#define FR_TRUNK 1536  // W1+W2 frags staged to LDS per block

// ---------------- prepack: weights -> MFMA A-operand fragment layout ----------------
// A = W^T tile: lane l holds W[k=32s+8*(l>>4)+e][16*mt + (l&15)], e=0..7.
__global__ __launch_bounds__(256)
void prepack_kernel(const float* __restrict__ dW1, const float* __restrict__ dW2,
                    const float* __restrict__ hw1, const float* __restrict__ hw2,
                    f16x8* __restrict__ pw)
{
    int F = blockIdx.x * 256 + threadIdx.x;
    if (F >= FR_TOT) return;
    int lane = F & 63, g = lane >> 4, c = lane & 15;
    const float* src;
    int s, mt, kmax;
    if (F < FR_W2) {                       // trunk W1 [100][64], zero-pad K to 128
        int r = F; s = r >> 8; mt = (r >> 6) & 3; src = dW1; kmax = 100;
    } else if (F < FR_HD) {                // trunk W2 [64][64]
        int r = F - FR_W2; s = r >> 8; mt = (r >> 6) & 3; src = dW2; kmax = 64;
    } else {                               // heads hw1/hw2 [5][64][64]
        int r = F - FR_HD; int ql = r >> 9; int q = ql >> 1; int l = ql & 1;
        int r2 = r & 511; s = r2 >> 8; mt = (r2 >> 6) & 3;
        src = (l ? hw2 : hw1) + q * 64 * 64; kmax = 64;
    }
    f16x8 v;
    #pragma unroll
    for (int e = 0; e < 8; ++e) {
        int k = 32 * s + 8 * g + e;
        int m = 16 * mt + c;
        float val = (k < kmax) ? src[k * 64 + m] : 0.0f;
        v[e] = (f16)val;
    }
    pw[F] = v;
}

// ---------------- global counting sort: hist -> scan -> scatter ----------------
__global__ __launch_bounds__(256)
void hist_kernel(const float* __restrict__ t, int* __restrict__ bh, int N)
{
    __shared__ int h[NB];
    if (threadIdx.x < NB) h[threadIdx.x] = 0;
    __syncthreads();
    const int s0 = blockIdx.x * SEG;
    const int e = min(SEG, N - s0);
    for (int p = threadIdx.x; p < e; p += 256) {
        int b = min((int)(t[s0 + p] * 5.0f), NB - 1);
        atomicAdd(&h[b], 1);
    }
    __syncthreads();
    if (threadIdx.x < NB) bh[blockIdx.x * NB + threadIdx.x] = h[threadIdx.x];
}

__global__ __launch_bounds__(64)
void scan_kernel(const int* __restrict__ bh, int* __restrict__ offs,
                 int* __restrict__ base, int nsb, int N)
{
    __shared__ int tot[NB];
    const int tid = threadIdx.x;
    if (tid < NB) {
        int run = 0;
        for (int blk = 0; blk < nsb; ++blk) {
            offs[blk * NB + tid] = run;
            run += bh[blk * NB + tid];
        }
        tot[tid] = run;
    }
    __syncthreads();
    if (tid == 0) {
        int r = 0;
        base[0] = 0;
        #pragma unroll
        for (int b = 0; b < NB; ++b) { r += tot[b]; base[b + 1] = r; }
    }
    __syncthreads();
    const int total = nsb * NB;
    for (int p = tid; p < total; p += 64) offs[p] += base[p % NB];
}

__global__ __launch_bounds__(256)
void scatter_kernel(const float* __restrict__ t, const int* __restrict__ offs,
                    int* __restrict__ perm, float* __restrict__ tsort, int N)
{
    __shared__ int lcur[NB];
    if (threadIdx.x < NB) lcur[threadIdx.x] = offs[blockIdx.x * NB + threadIdx.x];
    __syncthreads();
    const int s0 = blockIdx.x * SEG;
    const int e = min(SEG, N - s0);
    for (int p = threadIdx.x; p < e; p += 256) {
        float tv = t[s0 + p];
        int b = min((int)(tv * 5.0f), NB - 1);
        int slot = atomicAdd(&lcur[b], 1);
        perm[slot] = s0 + p;
        tsort[slot] = tv;
    }
}

// ---------------- main ----------------
struct XF { f16x8 v[4]; };

__device__ __forceinline__ f32x4 mfma16(f16x8 a, f16x8 b, f32x4 c) {
    return __builtin_amdgcn_mfma_f32_16x16x32_f16(a, b, c, 0, 0, 0);
}

__device__ __forceinline__ f16x8 ldw(const unsigned char* swf, int idx) {
    return *(const f16x8*)(swf + (idx << 4));
}

__device__ __forceinline__ void load_tile(float4* xr, const float* x, int iv, int g) {
    const float4* x4 = (const float4*)(x + (size_t)iv * DIN);  // rows 16B-aligned (400=25*16)
    #pragma unroll
    for (int s = 0; s < 3; ++s) { xr[2*s] = x4[8*s + 2*g]; xr[2*s+1] = x4[8*s + 2*g + 1]; }
    xr[6] = x4[24];
}

__device__ __forceinline__ void conv_tile(XF& xf, const float4* xr, int g) {
    #pragma unroll
    for (int s = 0; s < 3; ++s) {
        float4 a = xr[2*s], b = xr[2*s+1];
        xf.v[s][0]=(f16)a.x; xf.v[s][1]=(f16)a.y; xf.v[s][2]=(f16)a.z; xf.v[s][3]=(f16)a.w;
        xf.v[s][4]=(f16)b.x; xf.v[s][5]=(f16)b.y; xf.v[s][6]=(f16)b.z; xf.v[s][7]=(f16)b.w;
    }
    {
        const bool lo = (g == 0);          // k=96..99 valid only for g==0
        float4 a = xr[6];
        xf.v[3][0]=lo?(f16)a.x:(f16)0.f; xf.v[3][1]=lo?(f16)a.y:(f16)0.f;
        xf.v[3][2]=lo?(f16)a.z:(f16)0.f; xf.v[3][3]=lo?(f16)a.w:(f16)0.f;
        xf.v[3][4]=(f16)0.f; xf.v[3][5]=(f16)0.f; xf.v[3][6]=(f16)0.f; xf.v[3][7]=(f16)0.f;
    }
}

__device__ __forceinline__ void epi_plain(unsigned char* buf, int row, int g,
                                          const f32x4* acc, const float* bias) {
    #pragma unroll
    for (int mt = 0; mt < 4; ++mt) {
        const float* bb = &bias[16 * mt + 4 * g];
        union { f16 h[4]; unsigned long long u; } pk;
        #pragma unroll
        for (int r2 = 0; r2 < 4; ++r2) pk.h[r2] = (f16)fmaxf(acc[mt][r2] + bb[r2], 0.f);
        *(unsigned long long*)(buf + ((row * 128 + 32 * mt + 8 * g) ^ ((row & 7) << 4))) = pk.u;
    }
}

__device__ __forceinline__ void epi_t(unsigned char* buf, int row, int g, float rt,
                                      const f32x4* acc, const float* bias, const float* tw) {
    #pragma unroll
    for (int mt = 0; mt < 4; ++mt) {
        const float* bb = &bias[16 * mt + 4 * g];
        const float* tt = &tw[16 * mt + 4 * g];
        union { f16 h[4]; unsigned long long u; } pk;
        #pragma unroll
        for (int r2 = 0; r2 < 4; ++r2)
            pk.h[r2] = (f16)fmaxf(acc[mt][r2] + bb[r2] + rt * tt[r2], 0.f);
        *(unsigned long long*)(buf + ((row * 128 + 32 * mt + 8 * g) ^ ((row & 7) << 4))) = pk.u;
    }
}

__device__ __forceinline__ f16x8 lds_read_h(const unsigned char* buf, int row, int g, int s) {
    return *(const f16x8*)(buf + ((row * 128 + 64 * s + 16 * g) ^ ((row & 7) << 4)));
}

__global__ __launch_bounds__(NT, 3)
void drnet_main(const float* __restrict__ x,
                const float* __restrict__ db1, const float* __restrict__ db2,
                const float* __restrict__ hb1, const float* __restrict__ htw1,
                const float* __restrict__ hb2, const float* __restrict__ htw2,
                const float* __restrict__ hw3, const float* __restrict__ htw3,
                const float* __restrict__ hb3,
                const f16x8* __restrict__ pw,
                const int* __restrict__ perm, const float* __restrict__ tsort,
                const int* __restrict__ base,
                float* __restrict__ out, int N, int ntiles)
{
    __shared__ float sb1f[H], sb2f[H];
    __shared__ float shb1[NB * H], shw1t[NB * H], shb2[NB * H], shw2t[NB * H], sw3f[NB * H];
    __shared__ float shtw3[NB], shb3[NB];
    __shared__ __align__(16) unsigned char swf[FR_TRUNK * 16];   // 24.5 KB trunk frags
    __shared__ __align__(16) unsigned char hbuf[4][2][2048];     // per-wave A/B h-buffers

    const int tid = threadIdx.x;
    const int lane = tid & 63;
    const int wv = tid >> 6;
    const int g = lane >> 4;
    const int row = lane & 15;

    for (int p = tid; p < H; p += NT) { sb1f[p] = db1[p]; sb2f[p] = db2[p]; }
    for (int p = tid; p < NB * H; p += NT) {
        shb1[p] = hb1[p];  shw1t[p] = htw1[p];
        shb2[p] = hb2[p];  shw2t[p] = htw2[p];
        sw3f[p] = hw3[p];
    }
    if (tid < NB) { shtw3[tid] = htw3[tid]; shb3[tid] = hb3[tid]; }
    for (int p = tid; p < FR_TRUNK; p += NT)
        ((float4*)swf)[p] = ((const float4*)pw)[p];
    __syncthreads();   // the ONLY barrier; main loop is wave-autonomous

    const int b1 = base[1], b2 = base[2], b3 = base[3], b4 = base[4];

    // contiguous tile range per wave (sorted => <=2 head switches per wave)
    const int NW = gridDim.x * (NT / 64);
    const int gw = blockIdx.x * (NT / 64) + wv;
    const int twn = ntiles / NW, rem = ntiles % NW;
    const int tstart = gw * twn + min(gw, rem);
    const int tcnt = twn + (gw < rem ? 1 : 0);

    unsigned char* hA = hbuf[wv][0];
    unsigned char* hB = hbuf[wv][1];
    const f32x4 zero = {0.f, 0.f, 0.f, 0.f};

    int qcur = -1;
    f16x8 h1f[8], h2f[8];   // resident head-weight frags (64 VGPR)

    for (int ti = 0; ti < tcnt; ++ti) {
        const int tt = tstart + ti;
        const int slot = tt * 16 + row;
        const bool sval = slot < N;
        const int sl = sval ? slot : (N - 1);
        const int pidx = perm[sl];
        const float rt = tsort[sl];
        const int rq = (sl >= b1) + (sl >= b2) + (sl >= b3) + (sl >= b4);
        const int s0 = tt * 16, s15 = min(tt * 16 + 15, N - 1);
        const int qlo = (s0 >= b1) + (s0 >= b2) + (s0 >= b3) + (s0 >= b4);
        const int qhi = (s15 >= b1) + (s15 >= b2) + (s15 >= b3) + (s15 >= b4);

        float4 xr[7];
        load_tile(xr, x, pidx, g);
        XF xf;
        conv_tile(xf, xr, g);

        // ---- trunk L1 ----
        f32x4 acc[4] = {zero, zero, zero, zero};
        #pragma unroll
        for (int s = 0; s < 4; ++s)
            #pragma unroll
            for (int mt = 0; mt < 4; ++mt)
                acc[mt] = mfma16(ldw(swf, FR_W1 + (s * 4 + mt) * 64 + lane), xf.v[s], acc[mt]);
        epi_plain(hA, row, g, acc, sb1f);

        // ---- trunk L2 ----
        f32x4 acc2[4] = {zero, zero, zero, zero};
        #pragma unroll
        for (int s = 0; s < 2; ++s) {
            f16x8 hf = lds_read_h(hA, row, g, s);
            #pragma unroll
            for (int mt = 0; mt < 4; ++mt)
                acc2[mt] = mfma16(ldw(swf, FR_W2 + (s * 4 + mt) * 64 + lane), hf, acc2[mt]);
        }
        epi_plain(hB, row, g, acc2, sb2f);

        // ---- heads (q-loop uniform; usually 1 iteration) ----
        #pragma unroll 1
        for (int q = qlo; q <= qhi; ++q) {
            if (q != qcur) {                 // wave-uniform, rare (bin boundary)
                const f16x8* ph = pw + FR_HD + q * 1024;
                #pragma unroll
                for (int u = 0; u < 8; ++u) h1f[u] = ph[u * 64 + lane];
                #pragma unroll
                for (int u = 0; u < 8; ++u) h2f[u] = ph[512 + u * 64 + lane];
                qcur = q;
            }

            f32x4 a1[4] = {zero, zero, zero, zero};
            #pragma unroll
            for (int s = 0; s < 2; ++s) {
                f16x8 hf = lds_read_h(hB, row, g, s);
                #pragma unroll
                for (int mt = 0; mt < 4; ++mt)
                    a1[mt] = mfma16(h1f[s * 4 + mt], hf, a1[mt]);
            }
            epi_t(hA, row, g, rt, a1, &shb1[q * 64], &shw1t[q * 64]);

            f32x4 a2[4] = {zero, zero, zero, zero};
            #pragma unroll
            for (int s = 0; s < 2; ++s) {
                f16x8 hf = lds_read_h(hA, row, g, s);
                #pragma unroll
                for (int mt = 0; mt < 4; ++mt)
                    a2[mt] = mfma16(h2f[s * 4 + mt], hf, a2[mt]);
            }

            float pa = 0.f;
            #pragma unroll
            for (int mt = 0; mt < 4; ++mt) {
                const float* bb = &shb2[q * 64 + 16 * mt + 4 * g];
                const float* tw = &shw2t[q * 64 + 16 * mt + 4 * g];
                const float* w3 = &sw3f[q * 64 + 16 * mt + 4 * g];
                #pragma unroll
                for (int r2 = 0; r2 < 4; ++r2) {
                    float v = fmaxf(a2[mt][r2] + bb[r2] + rt * tw[r2], 0.f);
                    pa += v * w3[r2];
                }
            }
            pa += __shfl_xor(pa, 16, 64);
            pa += __shfl_xor(pa, 32, 64);
            if (lane < 16 && rq == q && sval)
                out[pidx] = pa + rt * shtw3[q] + shb3[q];
        }
    }
}

extern "C" void kernel_launch(void* const* d_in, const int* in_sizes, int n_in,
                              void* d_out, int out_size, void* d_ws, size_t ws_size,
                              hipStream_t stream) {
    const float* t    = (const float*)d_in[0];
    const float* x    = (const float*)d_in[1];
    const float* dW1  = (const float*)d_in[2];
    const float* db1  = (const float*)d_in[3];
    const float* dW2  = (const float*)d_in[4];
    const float* db2  = (const float*)d_in[5];
    const float* hw1  = (const float*)d_in[6];
    const float* htw1 = (const float*)d_in[7];
    const float* hb1  = (const float*)d_in[8];
    const float* hw2  = (const float*)d_in[9];
    const float* htw2 = (const float*)d_in[10];
    const float* hb2  = (const float*)d_in[11];
    const float* hw3  = (const float*)d_in[12];
    const float* htw3 = (const float*)d_in[13];
    const float* hb3  = (const float*)d_in[14];
    float* out = (float*)d_out;

    const int N = in_sizes[0];
    const int ntiles = (N + 15) / 16;
    const int nsb = (N + SEG - 1) / SEG;

    // d_ws layout
    char* ws = (char*)d_ws;
    f16x8* pw   = (f16x8*)ws;                                  // 106,496 B
    int*   bh   = (int*)(ws + 106496);                         // nsb*5 ints
    int*   offs = (int*)(ws + 106496 + ((nsb * NB * 4 + 15) & ~15));
    int*   base = (int*)((char*)offs + ((nsb * NB * 4 + 15) & ~15));
    int*   perm = (int*)((char*)base + 32);
    float* tsort= (float*)((char*)perm + (size_t)N * 4);

    prepack_kernel<<<(FR_TOT + 255) / 256, 256, 0, stream>>>(dW1, dW2, hw1, hw2, pw);
    hist_kernel<<<nsb, 256, 0, stream>>>(t, bh, N);
    scan_kernel<<<1, 64, 0, stream>>>(bh, offs, base, nsb, N);
    scatter_kernel<<<nsb, 256, 0, stream>>>(t, offs, perm, tsort, N);
    drnet_main<<<MAIN_BLOCKS, NT, 0, stream>>>(x, db1, db2, hb1, htw1, hb2, htw2,
                                               hw3, htw3, hb3, pw, perm, tsort, base,
                                               out, N, ntiles);
}

// Round 7
// 154.206 us; speedup vs baseline: 2.1972x; 2.1972x over previous
//
#include <hip/hip_runtime.h>

typedef _Float16 f16;
typedef _Float16 f16x8 __attribute__((ext_vector_type(8)));
typedef float f32x16 __attribute__((ext_vector_type(16)));

#define NB 5
#define DIN 100
#define NT 512
#define GRID 256
#define NWAVES (GRID * 8)

// fragment ids: W1 = [ks0..6][mt0..1] -> 14, W2 -> 8, heads: q*16 + layer*8 + ks*2 + mt
#define FID_W2 14
#define FID_HD 22
#define NFID   (FID_HD + NB * 16)   // 102
#define NENT   (NFID * 64)          // 6528 f16x8 entries

// A-frag layout (32x32x16): lane l holds W[k = 16*ks + 8*(l>>5) + e][feat = 32*mt + (l&31)]
__global__ __launch_bounds__(256)
void prepack_kernel(const float* __restrict__ dW1, const float* __restrict__ dW2,
                    const float* __restrict__ hw1, const float* __restrict__ hw2,
                    f16x8* __restrict__ pw)
{
    int E = blockIdx.x * 256 + threadIdx.x;
    if (E >= NENT) return;
    int lane = E & 63, fid = E >> 6;
    const float* src; int ks, mt, kmax;
    if (fid < FID_W2)      { int f = fid;          ks = f >> 1; mt = f & 1; src = dW1; kmax = 100; }
    else if (fid < FID_HD) { int f = fid - FID_W2; ks = f >> 1; mt = f & 1; src = dW2; kmax = 64; }
    else {
        int f = fid - FID_HD; int q = f >> 4; int r = f & 15;
        int layer = r >> 3; int rr = r & 7; ks = rr >> 1; mt = rr & 1;
        src = (layer ? hw2 : hw1) + q * 4096; kmax = 64;
    }
    f16x8 v;
    #pragma unroll
    for (int e = 0; e < 8; ++e) {
        int k = 16 * ks + 8 * (lane >> 5) + e;
        int m = 32 * mt + (lane & 31);
        v[e] = (k < kmax) ? (f16)src[k * 64 + m] : (f16)0.f;
    }
    pw[E] = v;
}

__device__ __forceinline__ f32x16 mfma32(f16x8 a, f16x8 b, f32x16 c) {
    return __builtin_amdgcn_mfma_f32_32x32x16_f16(a, b, c, 0, 0, 0);
}
__device__ __forceinline__ f32x16 vzero() {
    f32x16 z;
    #pragma unroll
    for (int i = 0; i < 16; ++i) z[i] = 0.f;
    return z;
}
__device__ __forceinline__ unsigned pk2(float a, float b) {   // rne f16 pair pack
    union { f16 h[2]; unsigned u; } z; z.h[0] = (f16)a; z.h[1] = (f16)b; return z.u;
}
__device__ __forceinline__ f16x8 frag4(unsigned a, unsigned b, unsigned c, unsigned d) {
    union { unsigned u[4]; f16x8 v; } z; z.u[0]=a; z.u[1]=b; z.u[2]=c; z.u[3]=d; return z.v;
}

// epi: relu(acc + bias [+ rt*tw]) -> 8 packed f16-pair words. feat = OFF + {0,1,2,3,8..11,16..19,24..27}
#define EPI8T(W, A, BIAS, TW, RT, OFF) { \
    const float4* bp_ = (const float4*)((BIAS) + (OFF)); \
    const float4* tp_ = (const float4*)((TW) + (OFF)); \
    float4 b0_=bp_[0], b1_=bp_[2], b2_=bp_[4], b3_=bp_[6]; \
    float4 t0_=tp_[0], t1_=tp_[2], t2_=tp_[4], t3_=tp_[6]; \
    W[0]=pk2(fmaxf(A[0]+b0_.x+(RT)*t0_.x,0.f), fmaxf(A[1]+b0_.y+(RT)*t0_.y,0.f)); \
    W[1]=pk2(fmaxf(A[2]+b0_.z+(RT)*t0_.z,0.f), fmaxf(A[3]+b0_.w+(RT)*t0_.w,0.f)); \
    W[2]=pk2(fmaxf(A[4]+b1_.x+(RT)*t1_.x,0.f), fmaxf(A[5]+b1_.y+(RT)*t1_.y,0.f)); \
    W[3]=pk2(fmaxf(A[6]+b1_.z+(RT)*t1_.z,0.f), fmaxf(A[7]+b1_.w+(RT)*t1_.w,0.f)); \
    W[4]=pk2(fmaxf(A[8]+b2_.x+(RT)*t2_.x,0.f), fmaxf(A[9]+b2_.y+(RT)*t2_.y,0.f)); \
    W[5]=pk2(fmaxf(A[10]+b2_.z+(RT)*t2_.z,0.f), fmaxf(A[11]+b2_.w+(RT)*t2_.w,0.f)); \
    W[6]=pk2(fmaxf(A[12]+b3_.x+(RT)*t3_.x,0.f), fmaxf(A[13]+b3_.y+(RT)*t3_.y,0.f)); \
    W[7]=pk2(fmaxf(A[14]+b3_.z+(RT)*t3_.z,0.f), fmaxf(A[15]+b3_.w+(RT)*t3_.w,0.f)); }

#define EPI8B(W, A, BIAS, OFF) { \
    const float4* bp_ = (const float4*)((BIAS) + (OFF)); \
    float4 b0_=bp_[0], b1_=bp_[2], b2_=bp_[4], b3_=bp_[6]; \
    W[0]=pk2(fmaxf(A[0]+b0_.x,0.f), fmaxf(A[1]+b0_.y,0.f)); \
    W[1]=pk2(fmaxf(A[2]+b0_.z,0.f), fmaxf(A[3]+b0_.w,0.f)); \
    W[2]=pk2(fmaxf(A[4]+b1_.x,0.f), fmaxf(A[5]+b1_.y,0.f)); \
    W[3]=pk2(fmaxf(A[6]+b1_.z,0.f), fmaxf(A[7]+b1_.w,0.f)); \
    W[4]=pk2(fmaxf(A[8]+b2_.x,0.f), fmaxf(A[9]+b2_.y,0.f)); \
    W[5]=pk2(fmaxf(A[10]+b2_.z,0.f), fmaxf(A[11]+b2_.w,0.f)); \
    W[6]=pk2(fmaxf(A[12]+b3_.x,0.f), fmaxf(A[13]+b3_.y,0.f)); \
    W[7]=pk2(fmaxf(A[14]+b3_.z,0.f), fmaxf(A[15]+b3_.w,0.f)); }

// assemble next layer's B-frag for one k-step from words Wm[jb..jb+3] (uses `lo` = lane<32)
#define MKB(dst, Wm, jb) { \
    unsigned s0_=__shfl_xor(Wm[jb+0],32,64), s1_=__shfl_xor(Wm[jb+1],32,64); \
    unsigned s2_=__shfl_xor(Wm[jb+2],32,64), s3_=__shfl_xor(Wm[jb+3],32,64); \
    dst = frag4(lo ? Wm[jb+0] : s2_, lo ? Wm[jb+1] : s3_, \
                lo ? s0_ : Wm[jb+2], lo ? s1_ : Wm[jb+3]); }

// final-layer partial: sum over lane's 16 feats of relu(a+b+rt*tw)*w3
#define ACC16(P, A, B2, T2, W3, RT, OFF) { \
    const float4* bb_=(const float4*)((B2)+(OFF)); const float4* tt_=(const float4*)((T2)+(OFF)); \
    const float4* ww_=(const float4*)((W3)+(OFF)); \
    float4 b0_=bb_[0],b1_=bb_[2],b2_=bb_[4],b3_=bb_[6]; \
    float4 t0_=tt_[0],t1_=tt_[2],t2_=tt_[4],t3_=tt_[6]; \
    float4 w0_=ww_[0],w1_=ww_[2],w2_=ww_[4],w3_=ww_[6]; \
    P += fmaxf(A[0]+b0_.x+(RT)*t0_.x,0.f)*w0_.x + fmaxf(A[1]+b0_.y+(RT)*t0_.y,0.f)*w0_.y \
       + fmaxf(A[2]+b0_.z+(RT)*t0_.z,0.f)*w0_.z + fmaxf(A[3]+b0_.w+(RT)*t0_.w,0.f)*w0_.w \
       + fmaxf(A[4]+b1_.x+(RT)*t1_.x,0.f)*w1_.x + fmaxf(A[5]+b1_.y+(RT)*t1_.y,0.f)*w1_.y \
       + fmaxf(A[6]+b1_.z+(RT)*t1_.z,0.f)*w1_.z + fmaxf(A[7]+b1_.w+(RT)*t1_.w,0.f)*w1_.w \
       + fmaxf(A[8]+b2_.x+(RT)*t2_.x,0.f)*w2_.x + fmaxf(A[9]+b2_.y+(RT)*t2_.y,0.f)*w2_.y \
       + fmaxf(A[10]+b2_.z+(RT)*t2_.z,0.f)*w2_.z + fmaxf(A[11]+b2_.w+(RT)*t2_.w,0.f)*w2_.w \
       + fmaxf(A[12]+b3_.x+(RT)*t3_.x,0.f)*w3_.x + fmaxf(A[13]+b3_.y+(RT)*t3_.y,0.f)*w3_.y \
       + fmaxf(A[14]+b3_.z+(RT)*t3_.z,0.f)*w3_.z + fmaxf(A[15]+b3_.w+(RT)*t3_.w,0.f)*w3_.w; }

__global__ __launch_bounds__(NT, 2)
void drnet_main(const float* __restrict__ t, const float* __restrict__ x,
                const float* __restrict__ db1, const float* __restrict__ db2,
                const float* __restrict__ hb1, const float* __restrict__ htw1,
                const float* __restrict__ hb2, const float* __restrict__ htw2,
                const float* __restrict__ hw3, const float* __restrict__ htw3,
                const float* __restrict__ hb3,
                const f16x8* __restrict__ pw,
                float* __restrict__ out, int N, int NG)
{
    __shared__ __align__(16) f16x8 swts[NENT];          // 102 KB: all weight frags
    __shared__ __align__(16) float sb1f[64], sb2f[64];
    __shared__ __align__(16) float shb1[NB*64], shw1t[NB*64], shb2[NB*64], shw2t[NB*64], sw3f[NB*64];
    __shared__ float shtw3[NB], shb3[NB];
    __shared__ unsigned short ssrt[8][64];
    __shared__ float sstv[8][64];
    __shared__ float sout[8][64];

    const int tid = threadIdx.x;
    const int lane = tid & 63;
    const int wv = tid >> 6;
    const int hi = lane >> 5;
    const int sm = lane & 31;
    const bool lo = (hi == 0);

    for (int p = tid; p < 64; p += NT) { sb1f[p] = db1[p]; sb2f[p] = db2[p]; }
    for (int p = tid; p < NB*64; p += NT) {
        shb1[p] = hb1[p]; shw1t[p] = htw1[p];
        shb2[p] = hb2[p]; shw2t[p] = htw2[p];
        sw3f[p] = hw3[p];
    }
    if (tid < NB) { shtw3[tid] = htw3[tid]; shb3[tid] = hb3[tid]; }
    for (int p = tid; p < NENT; p += NT)
        ((float4*)swts)[p] = ((const float4*)pw)[p];
    __syncthreads();   // ONLY barrier; the main loop is fully wave-autonomous

    #define TF(fid) swts[(fid)*64 + lane]

    const int gw = blockIdx.x * 8 + wv;
    float tpre = t[min(gw * 64 + lane, N - 1)];

    // per-tile compute: 32 sorted samples, everything in registers/LDS
    auto do_tile = [&](const f16x8* xb, int li, int rq, float rt, int qlo, int qhiR) {
        if (qlo >= NB) return;
        const int qhi = min(qhiR, NB - 1);

        // trunk L1: h1 = relu(W1^T x^T + b1)   (C: feat x sample)
        f32x16 a0 = vzero(), a1 = vzero();
        #pragma unroll
        for (int ks = 0; ks < 7; ++ks) {
            a0 = mfma32(TF(ks*2 + 0), xb[ks], a0);
            a1 = mfma32(TF(ks*2 + 1), xb[ks], a1);
        }
        unsigned WA[8], WB[8];
        EPI8B(WA, a0, sb1f, 4*hi);
        EPI8B(WB, a1, sb1f, 32 + 4*hi);
        f16x8 hb0, hb1_, hb2_, hb3_;
        MKB(hb0, WA, 0); MKB(hb1_, WA, 4); MKB(hb2_, WB, 0); MKB(hb3_, WB, 4);

        // trunk L2
        f32x16 c0 = vzero(), c1 = vzero();
        c0 = mfma32(TF(FID_W2+0), hb0, c0);  c1 = mfma32(TF(FID_W2+1), hb0, c1);
        c0 = mfma32(TF(FID_W2+2), hb1_, c0); c1 = mfma32(TF(FID_W2+3), hb1_, c1);
        c0 = mfma32(TF(FID_W2+4), hb2_, c0); c1 = mfma32(TF(FID_W2+5), hb2_, c1);
        c0 = mfma32(TF(FID_W2+6), hb3_, c0); c1 = mfma32(TF(FID_W2+7), hb3_, c1);
        unsigned UA[8], UB[8];
        EPI8B(UA, c0, sb2f, 4*hi);
        EPI8B(UB, c1, sb2f, 32 + 4*hi);
        f16x8 g0, g1, g2, g3;                 // h2 B-frags, reused across q-iters
        MKB(g0, UA, 0); MKB(g1, UA, 4); MKB(g2, UB, 0); MKB(g3, UB, 4);

        #pragma unroll 1
        for (int q = qlo; q <= qhi; ++q) {
            const int hf = FID_HD + q * 16;
            f32x16 d0 = vzero(), d1 = vzero();
            d0 = mfma32(TF(hf+0), g0, d0);  d1 = mfma32(TF(hf+1), g0, d1);
            d0 = mfma32(TF(hf+2), g1, d0);  d1 = mfma32(TF(hf+3), g1, d1);
            d0 = mfma32(TF(hf+4), g2, d0);  d1 = mfma32(TF(hf+5), g2, d1);
            d0 = mfma32(TF(hf+6), g3, d0);  d1 = mfma32(TF(hf+7), g3, d1);
            unsigned VA[8], VB[8];
            EPI8T(VA, d0, shb1 + q*64, shw1t + q*64, rt, 4*hi);
            EPI8T(VB, d1, shb1 + q*64, shw1t + q*64, rt, 32 + 4*hi);
            f16x8 e0, e1, e2, e3;
            MKB(e0, VA, 0); MKB(e1, VA, 4); MKB(e2, VB, 0); MKB(e3, VB, 4);

            f32x16 f0 = vzero(), f1 = vzero();
            f0 = mfma32(TF(hf+8),  e0, f0);  f1 = mfma32(TF(hf+9),  e0, f1);
            f0 = mfma32(TF(hf+10), e1, f0);  f1 = mfma32(TF(hf+11), e1, f1);
            f0 = mfma32(TF(hf+12), e2, f0);  f1 = mfma32(TF(hf+13), e2, f1);
            f0 = mfma32(TF(hf+14), e3, f0);  f1 = mfma32(TF(hf+15), e3, f1);

            float part = 0.f;
            ACC16(part, f0, shb2 + q*64, shw2t + q*64, sw3f + q*64, rt, 4*hi);
            ACC16(part, f1, shb2 + q*64, shw2t + q*64, sw3f + q*64, rt, 32 + 4*hi);
            part += __shfl_xor(part, 32, 64);
            if (lo && rq == q)
                sout[wv][li] = part + rt * shtw3[q] + shb3[q];
        }
    };

    #pragma unroll 1
    for (int g = gw; g < NG; g += NWAVES) {
        const int i0 = g * 64 + lane;
        const float tv = tpre;
        const int qme = (i0 < N) ? min((int)(tv * 5.0f), NB - 1) : NB;

        // ---- wave-local counting sort (ballot), no barriers ----
        const unsigned long long lowm = (1ull << lane) - 1ull;
        int pos = 0;
        #pragma unroll
        for (int b = 0; b <= NB; ++b) {
            unsigned long long mb = __ballot(qme == b);
            int ca = __popcll(mb), cb = __popcll(mb & lowm);
            pos += (b < qme) ? ca : ((b == qme) ? cb : 0);
        }
        ssrt[wv][pos] = (unsigned short)(lane | (qme << 8));
        sstv[wv][pos] = tv;
        __asm__ volatile("s_waitcnt lgkmcnt(0)" ::: "memory");

        const unsigned short pk0 = ssrt[wv][sm];
        const unsigned short pk1 = ssrt[wv][32 + sm];
        const int li0 = pk0 & 63, rq0 = pk0 >> 8;
        const int li1 = pk1 & 63, rq1 = pk1 >> 8;
        const float rt0 = sstv[wv][sm], rt1 = sstv[wv][32 + sm];
        const int qlo0 = ssrt[wv][0]  >> 8, qh0 = ssrt[wv][31] >> 8;
        const int qlo1 = ssrt[wv][32] >> 8, qh1 = ssrt[wv][63] >> 8;

        // ---- issue BOTH tiles' x loads up front (stay in flight under compute) ----
        const float4* xA = (const float4*)(x + (size_t)min(g*64 + li0, N - 1) * DIN);
        const float4* xB = (const float4*)(x + (size_t)min(g*64 + li1, N - 1) * DIN);
        float4 rA[13], rB[13];
        #pragma unroll
        for (int ks = 0; ks < 6; ++ks) { rA[2*ks] = xA[4*ks + 2*hi]; rA[2*ks+1] = xA[4*ks + 2*hi + 1]; }
        rA[12] = lo ? xA[24] : make_float4(0.f, 0.f, 0.f, 0.f);
        #pragma unroll
        for (int ks = 0; ks < 6; ++ks) { rB[2*ks] = xB[4*ks + 2*hi]; rB[2*ks+1] = xB[4*ks + 2*hi + 1]; }
        rB[12] = lo ? xB[24] : make_float4(0.f, 0.f, 0.f, 0.f);

        // prefetch next group's t (consumed next iteration)
        { int gn = g + NWAVES; tpre = (gn < NG) ? t[min(gn*64 + lane, N - 1)] : 0.f; }

        // ---- tile 0 ----
        f16x8 xb[7];
        #pragma unroll
        for (int ks = 0; ks < 6; ++ks)
            xb[ks] = frag4(pk2(rA[2*ks].x, rA[2*ks].y),   pk2(rA[2*ks].z, rA[2*ks].w),
                           pk2(rA[2*ks+1].x, rA[2*ks+1].y), pk2(rA[2*ks+1].z, rA[2*ks+1].w));
        xb[6] = frag4(pk2(rA[12].x, rA[12].y), pk2(rA[12].z, rA[12].w), 0u, 0u);
        do_tile(xb, li0, rq0, rt0, qlo0, qh0);

        // ---- tile 1 ----
        #pragma unroll
        for (int ks = 0; ks < 6; ++ks)
            xb[ks] = frag4(pk2(rB[2*ks].x, rB[2*ks].y),   pk2(rB[2*ks].z, rB[2*ks].w),
                           pk2(rB[2*ks+1].x, rB[2*ks+1].y), pk2(rB[2*ks+1].z, rB[2*ks+1].w));
        xb[6] = frag4(pk2(rB[12].x, rB[12].y), pk2(rB[12].z, rB[12].w), 0u, 0u);
        do_tile(xb, li1, rq1, rt1, qlo1, qh1);

        // ---- coalesced output flush ----
        __asm__ volatile("s_waitcnt lgkmcnt(0)" ::: "memory");
        const int ig = g * 64 + lane;
        if (ig < N) out[ig] = sout[wv][lane];
    }
    #undef TF
}

extern "C" void kernel_launch(void* const* d_in, const int* in_sizes, int n_in,
                              void* d_out, int out_size, void* d_ws, size_t ws_size,
                              hipStream_t stream) {
    const float* t    = (const float*)d_in[0];
    const float* x    = (const float*)d_in[1];
    const float* dW1  = (const float*)d_in[2];
    const float* db1  = (const float*)d_in[3];
    const float* dW2  = (const float*)d_in[4];
    const float* db2  = (const float*)d_in[5];
    const float* hw1  = (const float*)d_in[6];
    const float* htw1 = (const float*)d_in[7];
    const float* hb1  = (const float*)d_in[8];
    const float* hw2  = (const float*)d_in[9];
    const float* htw2 = (const float*)d_in[10];
    const float* hb2  = (const float*)d_in[11];
    const float* hw3  = (const float*)d_in[12];
    const float* htw3 = (const float*)d_in[13];
    const float* hb3  = (const float*)d_in[14];
    float* out = (float*)d_out;

    const int N = in_sizes[0];
    const int NG = (N + 63) / 64;
    f16x8* pw = (f16x8*)d_ws;   // NENT * 16 B = 104,448 B

    prepack_kernel<<<(NENT + 255) / 256, 256, 0, stream>>>(dW1, dW2, hw1, hw2, pw);
    drnet_main<<<GRID, NT, 0, stream>>>(t, x, db1, db2, hb1, htw1, hb2, htw2,
                                        hw3, htw3, hb3, pw, out, N, NG);
}

// Round 8
// 150.550 us; speedup vs baseline: 2.2505x; 1.0243x over previous
//
#include <hip/hip_runtime.h>

typedef _Float16 f16;
typedef _Float16 f16x8 __attribute__((ext_vector_type(8)));
typedef float f32x16 __attribute__((ext_vector_type(16)));

#define NB 5
#define DIN 100
#define NT 512
#define GRID 256
#define NWAVES (GRID * 8)

// fragment ids: W1 = [ks0..6][mt0..1] -> 14, W2 -> 8, heads: q*16 + layer*8 + ks*2 + mt
#define FID_W2 14
#define FID_HD 22
#define NFID   (FID_HD + NB * 16)   // 102
#define NENT   (NFID * 64)          // 6528 f16x8 entries

// A-frag layout (32x32x16): lane l holds W[k = 16*ks + 8*(l>>5) + e][feat = 32*mt + (l&31)]
__global__ __launch_bounds__(256)
void prepack_kernel(const float* __restrict__ dW1, const float* __restrict__ dW2,
                    const float* __restrict__ hw1, const float* __restrict__ hw2,
                    f16x8* __restrict__ pw)
{
    int E = blockIdx.x * 256 + threadIdx.x;
    if (E >= NENT) return;
    int lane = E & 63, fid = E >> 6;
    const float* src; int ks, mt, kmax;
    if (fid < FID_W2)      { int f = fid;          ks = f >> 1; mt = f & 1; src = dW1; kmax = 100; }
    else if (fid < FID_HD) { int f = fid - FID_W2; ks = f >> 1; mt = f & 1; src = dW2; kmax = 64; }
    else {
        int f = fid - FID_HD; int q = f >> 4; int r = f & 15;
        int layer = r >> 3; int rr = r & 7; ks = rr >> 1; mt = rr & 1;
        src = (layer ? hw2 : hw1) + q * 4096; kmax = 64;
    }
    f16x8 v;
    #pragma unroll
    for (int e = 0; e < 8; ++e) {
        int k = 16 * ks + 8 * (lane >> 5) + e;
        int m = 32 * mt + (lane & 31);
        v[e] = (k < kmax) ? (f16)src[k * 64 + m] : (f16)0.f;
    }
    pw[E] = v;
}

__device__ __forceinline__ f32x16 mfma32(f16x8 a, f16x8 b, f32x16 c) {
    return __builtin_amdgcn_mfma_f32_32x32x16_f16(a, b, c, 0, 0, 0);
}
__device__ __forceinline__ f32x16 vzero() {
    f32x16 z;
    #pragma unroll
    for (int i = 0; i < 16; ++i) z[i] = 0.f;
    return z;
}
__device__ __forceinline__ unsigned pk2(float a, float b) {   // rne f16 pair pack
    union { f16 h[2]; unsigned u; } z; z.h[0] = (f16)a; z.h[1] = (f16)b; return z.u;
}
__device__ __forceinline__ f16x8 frag4(unsigned a, unsigned b, unsigned c, unsigned d) {
    union { unsigned u[4]; f16x8 v; } z; z.u[0]=a; z.u[1]=b; z.u[2]=c; z.u[3]=d; return z.v;
}

// epi: relu(acc + bias [+ rt*tw]) -> 8 packed f16-pair words. feat = OFF + {0,1,2,3,8..11,16..19,24..27}
#define EPI8T(W, A, BIAS, TW, RT, OFF) { \
    const float4* bp_ = (const float4*)((BIAS) + (OFF)); \
    const float4* tp_ = (const float4*)((TW) + (OFF)); \
    float4 b0_=bp_[0], b1_=bp_[2], b2_=bp_[4], b3_=bp_[6]; \
    float4 t0_=tp_[0], t1_=tp_[2], t2_=tp_[4], t3_=tp_[6]; \
    W[0]=pk2(fmaxf(A[0]+b0_.x+(RT)*t0_.x,0.f), fmaxf(A[1]+b0_.y+(RT)*t0_.y,0.f)); \
    W[1]=pk2(fmaxf(A[2]+b0_.z+(RT)*t0_.z,0.f), fmaxf(A[3]+b0_.w+(RT)*t0_.w,0.f)); \
    W[2]=pk2(fmaxf(A[4]+b1_.x+(RT)*t1_.x,0.f), fmaxf(A[5]+b1_.y+(RT)*t1_.y,0.f)); \
    W[3]=pk2(fmaxf(A[6]+b1_.z+(RT)*t1_.z,0.f), fmaxf(A[7]+b1_.w+(RT)*t1_.w,0.f)); \
    W[4]=pk2(fmaxf(A[8]+b2_.x+(RT)*t2_.x,0.f), fmaxf(A[9]+b2_.y+(RT)*t2_.y,0.f)); \
    W[5]=pk2(fmaxf(A[10]+b2_.z+(RT)*t2_.z,0.f), fmaxf(A[11]+b2_.w+(RT)*t2_.w,0.f)); \
    W[6]=pk2(fmaxf(A[12]+b3_.x+(RT)*t3_.x,0.f), fmaxf(A[13]+b3_.y+(RT)*t3_.y,0.f)); \
    W[7]=pk2(fmaxf(A[14]+b3_.z+(RT)*t3_.z,0.f), fmaxf(A[15]+b3_.w+(RT)*t3_.w,0.f)); }

#define EPI8B(W, A, BIAS, OFF) { \
    const float4* bp_ = (const float4*)((BIAS) + (OFF)); \
    float4 b0_=bp_[0], b1_=bp_[2], b2_=bp_[4], b3_=bp_[6]; \
    W[0]=pk2(fmaxf(A[0]+b0_.x,0.f), fmaxf(A[1]+b0_.y,0.f)); \
    W[1]=pk2(fmaxf(A[2]+b0_.z,0.f), fmaxf(A[3]+b0_.w,0.f)); \
    W[2]=pk2(fmaxf(A[4]+b1_.x,0.f), fmaxf(A[5]+b1_.y,0.f)); \
    W[3]=pk2(fmaxf(A[6]+b1_.z,0.f), fmaxf(A[7]+b1_.w,0.f)); \
    W[4]=pk2(fmaxf(A[8]+b2_.x,0.f), fmaxf(A[9]+b2_.y,0.f)); \
    W[5]=pk2(fmaxf(A[10]+b2_.z,0.f), fmaxf(A[11]+b2_.w,0.f)); \
    W[6]=pk2(fmaxf(A[12]+b3_.x,0.f), fmaxf(A[13]+b3_.y,0.f)); \
    W[7]=pk2(fmaxf(A[14]+b3_.z,0.f), fmaxf(A[15]+b3_.w,0.f)); }

// assemble next layer's B-frag for one k-step from words Wm[jb..jb+3] (uses `lo` = lane<32)
#define MKB(dst, Wm, jb) { \
    unsigned s0_=__shfl_xor(Wm[jb+0],32,64), s1_=__shfl_xor(Wm[jb+1],32,64); \
    unsigned s2_=__shfl_xor(Wm[jb+2],32,64), s3_=__shfl_xor(Wm[jb+3],32,64); \
    dst = frag4(lo ? Wm[jb+0] : s2_, lo ? Wm[jb+1] : s3_, \
                lo ? s0_ : Wm[jb+2], lo ? s1_ : Wm[jb+3]); }

// final-layer partial: sum over lane's 16 feats of relu(a+b+rt*tw)*w3
#define ACC16(P, A, B2, T2, W3, RT, OFF) { \
    const float4* bb_=(const float4*)((B2)+(OFF)); const float4* tt_=(const float4*)((T2)+(OFF)); \
    const float4* ww_=(const float4*)((W3)+(OFF)); \
    float4 b0_=bb_[0],b1_=bb_[2],b2_=bb_[4],b3_=bb_[6]; \
    float4 t0_=tt_[0],t1_=tt_[2],t2_=tt_[4],t3_=tt_[6]; \
    float4 w0_=ww_[0],w1_=ww_[2],w2_=ww_[4],w3_=ww_[6]; \
    P += fmaxf(A[0]+b0_.x+(RT)*t0_.x,0.f)*w0_.x + fmaxf(A[1]+b0_.y+(RT)*t0_.y,0.f)*w0_.y \
       + fmaxf(A[2]+b0_.z+(RT)*t0_.z,0.f)*w0_.z + fmaxf(A[3]+b0_.w+(RT)*t0_.w,0.f)*w0_.w \
       + fmaxf(A[4]+b1_.x+(RT)*t1_.x,0.f)*w1_.x + fmaxf(A[5]+b1_.y+(RT)*t1_.y,0.f)*w1_.y \
       + fmaxf(A[6]+b1_.z+(RT)*t1_.z,0.f)*w1_.z + fmaxf(A[7]+b1_.w+(RT)*t1_.w,0.f)*w1_.w \
       + fmaxf(A[8]+b2_.x+(RT)*t2_.x,0.f)*w2_.x + fmaxf(A[9]+b2_.y+(RT)*t2_.y,0.f)*w2_.y \
       + fmaxf(A[10]+b2_.z+(RT)*t2_.z,0.f)*w2_.z + fmaxf(A[11]+b2_.w+(RT)*t2_.w,0.f)*w2_.w \
       + fmaxf(A[12]+b3_.x+(RT)*t3_.x,0.f)*w3_.x + fmaxf(A[13]+b3_.y+(RT)*t3_.y,0.f)*w3_.y \
       + fmaxf(A[14]+b3_.z+(RT)*t3_.z,0.f)*w3_.z + fmaxf(A[15]+b3_.w+(RT)*t3_.w,0.f)*w3_.w; }

__global__ __launch_bounds__(NT, 2)
void drnet_main(const float* __restrict__ t, const float* __restrict__ x,
                const float* __restrict__ db1, const float* __restrict__ db2,
                const float* __restrict__ hb1, const float* __restrict__ htw1,
                const float* __restrict__ hb2, const float* __restrict__ htw2,
                const float* __restrict__ hw3, const float* __restrict__ htw3,
                const float* __restrict__ hb3,
                const f16x8* __restrict__ pw,
                float* __restrict__ out, int N, int NG)
{
    __shared__ __align__(16) f16x8 swts[NENT];          // 102 KB: all weight frags
    __shared__ __align__(16) float sb1f[64], sb2f[64];
    __shared__ __align__(16) float shb1[NB*64], shw1t[NB*64], shb2[NB*64], shw2t[NB*64], sw3f[NB*64];
    __shared__ float shtw3[NB], shb3[NB];
    __shared__ unsigned short ssrt[8][64];
    __shared__ float sstv[8][64];
    __shared__ float sout[8][64];

    const int tid = threadIdx.x;
    const int lane = tid & 63;
    const int wv = tid >> 6;
    const int hi = lane >> 5;
    const int sm = lane & 31;
    const bool lo = (hi == 0);

    for (int p = tid; p < 64; p += NT) { sb1f[p] = db1[p]; sb2f[p] = db2[p]; }
    for (int p = tid; p < NB*64; p += NT) {
        shb1[p] = hb1[p]; shw1t[p] = htw1[p];
        shb2[p] = hb2[p]; shw2t[p] = htw2[p];
        sw3f[p] = hw3[p];
    }
    if (tid < NB) { shtw3[tid] = htw3[tid]; shb3[tid] = hb3[tid]; }
    for (int p = tid; p < NENT; p += NT)
        ((float4*)swts)[p] = ((const float4*)pw)[p];
    __syncthreads();   // ONLY barrier; the main loop is fully wave-autonomous

    #define TF(fid) swts[(fid)*64 + lane]

    // per-tile compute: 32 sorted samples, everything in registers/LDS (r7-verified)
    auto do_tile = [&](const f16x8* xb, int li, int rq, float rt, int qlo, int qhiR) {
        if (qlo >= NB) return;
        const int qhi = min(qhiR, NB - 1);

        f32x16 a0 = vzero(), a1 = vzero();
        #pragma unroll
        for (int ks = 0; ks < 7; ++ks) {
            a0 = mfma32(TF(ks*2 + 0), xb[ks], a0);
            a1 = mfma32(TF(ks*2 + 1), xb[ks], a1);
        }
        unsigned WA[8], WB[8];
        EPI8B(WA, a0, sb1f, 4*hi);
        EPI8B(WB, a1, sb1f, 32 + 4*hi);
        f16x8 hb0, hb1_, hb2_, hb3_;
        MKB(hb0, WA, 0); MKB(hb1_, WA, 4); MKB(hb2_, WB, 0); MKB(hb3_, WB, 4);

        f32x16 c0 = vzero(), c1 = vzero();
        c0 = mfma32(TF(FID_W2+0), hb0, c0);  c1 = mfma32(TF(FID_W2+1), hb0, c1);
        c0 = mfma32(TF(FID_W2+2), hb1_, c0); c1 = mfma32(TF(FID_W2+3), hb1_, c1);
        c0 = mfma32(TF(FID_W2+4), hb2_, c0); c1 = mfma32(TF(FID_W2+5), hb2_, c1);
        c0 = mfma32(TF(FID_W2+6), hb3_, c0); c1 = mfma32(TF(FID_W2+7), hb3_, c1);
        unsigned UA[8], UB[8];
        EPI8B(UA, c0, sb2f, 4*hi);
        EPI8B(UB, c1, sb2f, 32 + 4*hi);
        f16x8 g0, g1, g2, g3;
        MKB(g0, UA, 0); MKB(g1, UA, 4); MKB(g2, UB, 0); MKB(g3, UB, 4);

        #pragma unroll 1
        for (int q = qlo; q <= qhi; ++q) {
            const int hf = FID_HD + q * 16;
            f32x16 d0 = vzero(), d1 = vzero();
            d0 = mfma32(TF(hf+0), g0, d0);  d1 = mfma32(TF(hf+1), g0, d1);
            d0 = mfma32(TF(hf+2), g1, d0);  d1 = mfma32(TF(hf+3), g1, d1);
            d0 = mfma32(TF(hf+4), g2, d0);  d1 = mfma32(TF(hf+5), g2, d1);
            d0 = mfma32(TF(hf+6), g3, d0);  d1 = mfma32(TF(hf+7), g3, d1);
            unsigned VA[8], VB[8];
            EPI8T(VA, d0, shb1 + q*64, shw1t + q*64, rt, 4*hi);
            EPI8T(VB, d1, shb1 + q*64, shw1t + q*64, rt, 32 + 4*hi);
            f16x8 e0, e1, e2, e3;
            MKB(e0, VA, 0); MKB(e1, VA, 4); MKB(e2, VB, 0); MKB(e3, VB, 4);

            f32x16 f0 = vzero(), f1 = vzero();
            f0 = mfma32(TF(hf+8),  e0, f0);  f1 = mfma32(TF(hf+9),  e0, f1);
            f0 = mfma32(TF(hf+10), e1, f0);  f1 = mfma32(TF(hf+11), e1, f1);
            f0 = mfma32(TF(hf+12), e2, f0);  f1 = mfma32(TF(hf+13), e2, f1);
            f0 = mfma32(TF(hf+14), e3, f0);  f1 = mfma32(TF(hf+15), e3, f1);

            float part = 0.f;
            ACC16(part, f0, shb2 + q*64, shw2t + q*64, sw3f + q*64, rt, 4*hi);
            ACC16(part, f1, shb2 + q*64, shw2t + q*64, sw3f + q*64, rt, 32 + 4*hi);
            part += __shfl_xor(part, 32, 64);
            if (lo && rq == q)
                sout[wv][li] = part + rt * shtw3[q] + shb3[q];
        }
    };

    // wave-local ballot counting sort of one 64-sample window (r7-verified)
    auto sortw = [&](int gn, float tvn) {
        const int i0 = gn * 64 + lane;
        const int qme = (i0 < N) ? min((int)(tvn * 5.0f), NB - 1) : NB;
        const unsigned long long lowm = (1ull << lane) - 1ull;
        int pos = 0;
        #pragma unroll
        for (int b = 0; b <= NB; ++b) {
            unsigned long long mb = __ballot(qme == b);
            int ca = __popcll(mb), cb = __popcll(mb & lowm);
            pos += (b < qme) ? ca : ((b == qme) ? cb : 0);
        }
        ssrt[wv][pos] = (unsigned short)(lane | (qme << 8));
        sstv[wv][pos] = tvn;
        __asm__ volatile("s_waitcnt lgkmcnt(0)" ::: "memory");
    };

    auto issue_x = [&](float4* r, int gn, int li) {
        const float4* xp = (const float4*)(x + (size_t)min(gn * 64 + li, N - 1) * DIN);
        #pragma unroll
        for (int ks = 0; ks < 6; ++ks) { r[2*ks] = xp[4*ks + 2*hi]; r[2*ks+1] = xp[4*ks + 2*hi + 1]; }
        r[12] = lo ? xp[24] : make_float4(0.f, 0.f, 0.f, 0.f);
    };

    auto convert = [&](f16x8* xb, const float4* r) {
        #pragma unroll
        for (int ks = 0; ks < 6; ++ks)
            xb[ks] = frag4(pk2(r[2*ks].x, r[2*ks].y),   pk2(r[2*ks].z, r[2*ks].w),
                           pk2(r[2*ks+1].x, r[2*ks+1].y), pk2(r[2*ks+1].z, r[2*ks+1].w));
        xb[6] = frag4(pk2(r[12].x, r[12].y), pk2(r[12].z, r[12].w), 0u, 0u);
    };

    const int gw = blockIdx.x * 8 + wv;
    const int S = NWAVES;

    float4 raw0[13], raw1[13];
    float treg = 0.f;
    int g = gw;
    if (g < NG) {
        treg = t[min(g * 64 + lane, N - 1)];
        sortw(g, treg);                                   // window g sorted
        { int li = ssrt[wv][sm] & 63; issue_x(raw0, g, li); }   // T0(g) in flight
        { int gn = g + S; treg = (gn < NG) ? t[min(gn * 64 + lane, N - 1)] : 0.f; }
    }

    // INVARIANT at loop top: ssrt/sstv = window g; raw0 = T0(g) in flight; treg = t(g+S)
    #pragma unroll 1
    for (; g < NG; g += S) {
        // extract BOTH tile descriptors into regs before any overwrite
        const unsigned short pk0 = ssrt[wv][sm], pk1 = ssrt[wv][32 + sm];
        const int li0 = pk0 & 63, rq0 = pk0 >> 8;
        const int li1 = pk1 & 63, rq1 = pk1 >> 8;
        const float rt0 = sstv[wv][sm], rt1 = sstv[wv][32 + sm];
        const int qlo0 = ssrt[wv][0]  >> 8, qh0 = ssrt[wv][31] >> 8;
        const int qlo1 = ssrt[wv][32] >> 8, qh1 = ssrt[wv][63] >> 8;

        issue_x(raw1, g, li1);                 // T1(g) loads join the queue first
        f16x8 xb0[7], xb1[7];
        convert(xb0, raw0);                    // waits raw0 only (raw1 stays in flight)
        __builtin_amdgcn_sched_barrier(0);     // pin: loads issued before tile0 compute
        do_tile(xb0, li0, rq0, rt0, qlo0, qh0);
        __builtin_amdgcn_sched_barrier(0);     // pin: raw1 wait not hoisted above tile0

        const bool last = (g + S >= NG);
        if (!last) {
            sortw(g + S, treg);                // next window's sort (t prefetched 1 window ago)
            { int gn2 = g + 2 * S; treg = (gn2 < NG) ? t[min(gn2 * 64 + lane, N - 1)] : 0.f; }
            { int li = ssrt[wv][sm] & 63; issue_x(raw0, g + S, li); }  // T0(g+S) in flight
            __builtin_amdgcn_sched_barrier(0); // pin: next-window loads issued before tile1
        }
        convert(xb1, raw1);                    // counted wait: raw0(next) stays in flight
        do_tile(xb1, li1, rq1, rt1, qlo1, qh1);

        __asm__ volatile("s_waitcnt lgkmcnt(0)" ::: "memory");
        const int ig = g * 64 + lane;
        if (ig < N) out[ig] = sout[wv][lane];  // coalesced flush
    }
    #undef TF
}

extern "C" void kernel_launch(void* const* d_in, const int* in_sizes, int n_in,
                              void* d_out, int out_size, void* d_ws, size_t ws_size,
                              hipStream_t stream) {
    const float* t    = (const float*)d_in[0];
    const float* x    = (const float*)d_in[1];
    const float* dW1  = (const float*)d_in[2];
    const float* db1  = (const float*)d_in[3];
    const float* dW2  = (const float*)d_in[4];
    const float* db2  = (const float*)d_in[5];
    const float* hw1  = (const float*)d_in[6];
    const float* htw1 = (const float*)d_in[7];
    const float* hb1  = (const float*)d_in[8];
    const float* hw2  = (const float*)d_in[9];
    const float* htw2 = (const float*)d_in[10];
    const float* hb2  = (const float*)d_in[11];
    const float* hw3  = (const float*)d_in[12];
    const float* htw3 = (const float*)d_in[13];
    const float* hb3  = (const float*)d_in[14];
    float* out = (float*)d_out;

    const int N = in_sizes[0];
    const int NG = (N + 63) / 64;
    f16x8* pw = (f16x8*)d_ws;   // NENT * 16 B = 104,448 B

    prepack_kernel<<<(NENT + 255) / 256, 256, 0, stream>>>(dW1, dW2, hw1, hw2, pw);
    drnet_main<<<GRID, NT, 0, stream>>>(t, x, db1, db2, hb1, htw1, hb2, htw2,
                                        hw3, htw3, hb3, pw, out, N, NG);
}